// Round 1
// baseline (24.350 us; speedup 1.0000x reference)
//
#include <hip/hip_runtime.h>

#define EPS_VAR 0.001f

__device__ __forceinline__ double wave_reduce(double v) {
    #pragma unroll
    for (int off = 32; off > 0; off >>= 1)
        v += __shfl_down(v, off, 64);
    return v;
}

// Pass 1: grid-stride over valid indices, per-thread double accumulation,
// block reduce -> 5 doubles per block in workspace.
__global__ __launch_bounds__(256) void rpn_pass1(
    const float* __restrict__ pred,
    const float* __restrict__ unc,
    const float* __restrict__ cls,
    const float* __restrict__ gt,
    const int* __restrict__ lab,
    const int* __restrict__ vi,
    int V,
    double* __restrict__ out_part) {

    double s_cls = 0.0, s_pos = 0.0, s_neg = 0.0;
    int n_pos = 0, n_neg = 0;

    const int stride = gridDim.x * blockDim.x;
    for (int i = blockIdx.x * blockDim.x + threadIdx.x; i < V; i += stride) {
        const int idx = vi[i];
        const int l = lab[idx];

        // 2-class cross entropy: lse - logits[label]
        const float2 lg = *reinterpret_cast<const float2*>(cls + 2ll * idx);
        const float m = fmaxf(lg.x, lg.y);
        const float lse = m + logf(expf(lg.x - m) + expf(lg.y - m));
        s_cls += (double)(lse - ((l == 1) ? lg.y : lg.x));

        const float4 u = *reinterpret_cast<const float4*>(unc + 4ll * idx);
        const float v0 = EPS_VAR + u.x * u.x;
        const float v1 = EPS_VAR + u.y * u.y;
        const float v2 = EPS_VAR + u.z * u.z;
        const float v3 = EPS_VAR + u.w * u.w;

        if (l == 1) {
            const float4 p = *reinterpret_cast<const float4*>(pred + 4ll * idx);
            const float4 g = *reinterpret_cast<const float4*>(gt + 4ll * idx);
            const float d0 = p.x - g.x, d1 = p.y - g.y;
            const float d2 = p.z - g.z, d3 = p.w - g.w;
            const float t = 0.5f * (d0 * d0 / v0 + d1 * d1 / v1 +
                                    d2 * d2 / v2 + d3 * d3 / v3)
                          + 0.5f * (logf(v0) + logf(v1) + logf(v2) + logf(v3));
            s_pos += (double)t;
            n_pos++;
        } else {
            const float t = 1.0f / v0 + 1.0f / v1 + 1.0f / v2 + 1.0f / v3;
            s_neg += (double)t;
            n_neg++;
        }
    }

    // block reduction: wave shuffle then LDS across the 4 waves
    __shared__ double sh[4][5];
    const double r0 = wave_reduce(s_cls);
    const double r1 = wave_reduce(s_pos);
    const double r2 = wave_reduce(s_neg);
    const double r3 = wave_reduce((double)n_pos);
    const double r4 = wave_reduce((double)n_neg);

    const int wave = threadIdx.x >> 6;
    if ((threadIdx.x & 63) == 0) {
        sh[wave][0] = r0; sh[wave][1] = r1; sh[wave][2] = r2;
        sh[wave][3] = r3; sh[wave][4] = r4;
    }
    __syncthreads();
    if (threadIdx.x == 0) {
        double a0 = 0, a1 = 0, a2 = 0, a3 = 0, a4 = 0;
        #pragma unroll
        for (int w = 0; w < 4; ++w) {
            a0 += sh[w][0]; a1 += sh[w][1]; a2 += sh[w][2];
            a3 += sh[w][3]; a4 += sh[w][4];
        }
        double* o = out_part + 5ll * blockIdx.x;
        o[0] = a0; o[1] = a1; o[2] = a2; o[3] = a3; o[4] = a4;
    }
}

// Pass 2: one block reduces all per-block partials, writes final scalar.
__global__ __launch_bounds__(256) void rpn_pass2(
    const double* __restrict__ part, int nb, int V, float* __restrict__ out) {

    double a0 = 0, a1 = 0, a2 = 0, a3 = 0, a4 = 0;
    for (int i = threadIdx.x; i < nb; i += blockDim.x) {
        const double* p = part + 5ll * i;
        a0 += p[0]; a1 += p[1]; a2 += p[2]; a3 += p[3]; a4 += p[4];
    }

    __shared__ double sh[4][5];
    a0 = wave_reduce(a0);
    a1 = wave_reduce(a1);
    a2 = wave_reduce(a2);
    a3 = wave_reduce(a3);
    a4 = wave_reduce(a4);

    const int wave = threadIdx.x >> 6;
    if ((threadIdx.x & 63) == 0) {
        sh[wave][0] = a0; sh[wave][1] = a1; sh[wave][2] = a2;
        sh[wave][3] = a3; sh[wave][4] = a4;
    }
    __syncthreads();
    if (threadIdx.x == 0) {
        double t0 = 0, t1 = 0, t2 = 0, t3 = 0, t4 = 0;
        #pragma unroll
        for (int w = 0; w < 4; ++w) {
            t0 += sh[w][0]; t1 += sh[w][1]; t2 += sh[w][2];
            t3 += sh[w][3]; t4 += sh[w][4];
        }
        const double class_loss = t0 / (double)V;
        const double reg_loss = t1 / t3 + t2 / t4;
        out[0] = (float)(class_loss + reg_loss);
    }
}

extern "C" void kernel_launch(void* const* d_in, const int* in_sizes, int n_in,
                              void* d_out, int out_size, void* d_ws, size_t ws_size,
                              hipStream_t stream) {
    const float* pred = (const float*)d_in[0];
    const float* unc  = (const float*)d_in[1];
    const float* cls  = (const float*)d_in[2];
    const float* gt   = (const float*)d_in[3];
    const int*   lab  = (const int*)d_in[4];
    const int*   vi   = (const int*)d_in[5];
    const int V = in_sizes[5];

    const int NB = 1024;  // 1024 blocks * 256 thr = 262144 threads, ~2 elems each
    double* part = (double*)d_ws;  // NB * 5 doubles = 40 KB

    rpn_pass1<<<NB, 256, 0, stream>>>(pred, unc, cls, gt, lab, vi, V, part);
    rpn_pass2<<<1, 256, 0, stream>>>(part, NB, V, (float*)d_out);
}